// Round 13
// baseline (126.368 us; speedup 1.0000x reference)
//
#include <hip/hip_runtime.h>

#define B_ 4
#define S_ 4096
#define T_ 4096
#define NH_ 16
#define CPB 32             // columns per block = 128B rows (full cache lines)
#define CPW 2              // columns per wave (16 waves/block)
#define ROWS 64            // s-rows per LDS tile
#define NTILE (S_ / ROWS)  // 64
#define TPB 2              // tiles per barrier phase
#define NPH (NTILE / TPB)  // 32 phases
#define LDSP 33            // padded LDS row stride (dwords); odd -> bank permutation
#define NCG (T_ / CPB)     // 128 column groups

typedef unsigned long long u64;

// DPP row_shr:1 — shift by one lane within each 16-lane row (VALU-only; keeps the
// serial insert chain off the LDS pipe). Only lanes 0-15 are consumed.
__device__ __forceinline__ float dpp_shr1_f(float v) {
    return __int_as_float(__builtin_amdgcn_update_dpp(
        0, __float_as_int(v), 0x111 /*row_shr:1*/, 0xF, 0xF, true));
}
__device__ __forceinline__ int dpp_shr1_i(int v) {
    return __builtin_amdgcn_update_dpp(0, v, 0x111, 0xF, 0xF, true);
}
__device__ __forceinline__ float d2_rn(float x, float y) {
    return __fadd_rn(__fmul_rn(x, x), __fmul_rn(y, y));   // bit-identical to np
}

// ---------------- Kernel A: transposed top-16 scan, 2 tiles/barrier ----------------
// grid = B * NCG = 512 blocks x 1024 threads (16 waves) = 2 blocks/CU = 8 waves/SIMD.
// Staging rebalanced across ALL 16 waves: thread t stages unit (tile sub=t>>9,
// row=(t>>3)&63, chunk=(t&7)*4) -- loads cx4+cy4, writes 4 d2 to LDS. One barrier
// per 2 tiles (32 vs r12's 64): halves barrier latency + straggler tax.
// Tile 0 seeds the sorted-16 via cross-lane bitonic sort-64; tiles 1+ use the
// ballot-skip + readlane/DPP insert chain (prune-free, tau once per tile).
__global__ __launch_bounds__(1024, 8) void topk_scan(
    const float* __restrict__ coords,   // [2][B][S][T]
    float* __restrict__ outW,           // [B][T][NH]
    int*   __restrict__ outI,           // [B][T][NH]
    float* __restrict__ partials)       // [512][NH] per-block denom partials
{
    __shared__ float lds[2][TPB][ROWS * LDSP];     // d2 only: 2 phases x 2 tiles
    __shared__ float red[16 * NH_];

    const int bid  = blockIdx.x;
    const int b    = bid >> 7;
    const int c0   = (bid & (NCG - 1)) * CPB;
    const int tid  = threadIdx.x;
    const int w    = tid >> 6;
    const int lane = tid & 63;

    const size_t plane = (size_t)B_ * S_ * T_;
    // staging map: sub = tid>>9 (which tile of the phase), row = (tid>>3)&63,
    // chunk = (tid&7)*4. 8 consecutive threads cover one 128B line.
    const int sub  = tid >> 9;
    const int srow = (tid >> 3) & 63;
    const int scol = (tid & 7) * 4;
    const float* g0 = coords + (size_t)b * S_ * T_ + (size_t)srow * T_ + (c0 + scol);
    const float* g1 = g0 + plane;
    float* wb0 = &lds[0][sub][srow * LDSP + scol];
    float* wb1 = &lds[1][sub][srow * LDSP + scol];

    // lane-distributed sorted lists: lane j (<16) holds slot j of each owned column
    float lv[CPW]; int li[CPW]; float tau[CPW];
#pragma unroll
    for (int cc = 0; cc < CPW; ++cc) {
        lv[cc]  = __int_as_float(0x7f800000);
        li[cc]  = 0;
        tau[cc] = __int_as_float(0x7f800000);
    }

    // prologue: stage phase-0 tiles {0,1}; prefetch phase-1 tiles {2,3} into regs
    float4 ax = *(const float4*)(g0 + (size_t)sub * ROWS * T_);
    float4 ay = *(const float4*)(g1 + (size_t)sub * ROWS * T_);
    wb0[0] = d2_rn(ax.x, ay.x); wb0[1] = d2_rn(ax.y, ay.y);
    wb0[2] = d2_rn(ax.z, ay.z); wb0[3] = d2_rn(ax.w, ay.w);
    ax = *(const float4*)(g0 + (size_t)(TPB + sub) * ROWS * T_);
    ay = *(const float4*)(g1 + (size_t)(TPB + sub) * ROWS * T_);
    __syncthreads();                          // phase-0 buffer visible

#pragma unroll 1
    for (int p = 0; p < NPH; ++p) {
        // stage phase p+1 tiles (in regs) into lds[(p+1)&1]; issue loads for p+2
        if (p + 1 < NPH) {
            float* wb = (p & 1) ? wb0 : wb1;
            wb[0] = d2_rn(ax.x, ay.x); wb[1] = d2_rn(ax.y, ay.y);
            wb[2] = d2_rn(ax.z, ay.z); wb[3] = d2_rn(ax.w, ay.w);
        }
        if (p + 2 < NPH) {
            ax = *(const float4*)(g0 + (size_t)(TPB * (p + 2) + sub) * ROWS * T_);
            ay = *(const float4*)(g1 + (size_t)(TPB * (p + 2) + sub) * ROWS * T_);
        }

        // consume tiles 2p, 2p+1 from lds[p&1]
#pragma unroll
        for (int s2 = 0; s2 < TPB; ++s2) {
            const int k = TPB * p + s2;
            const float* rb = lds[p & 1][s2];
            if (k == 0) {
                // ---- tile-0 seed: bitonic sort-64 of (d2, s) keys across lanes ----
#pragma unroll
                for (int cc = 0; cc < CPW; ++cc) {
                    const float d2 = rb[lane * LDSP + (w * CPW + cc)];
                    u64 key = ((u64)(unsigned)__float_as_int(d2) << 32) | (unsigned)lane;
#pragma unroll
                    for (int bk = 2; bk <= 64; bk <<= 1) {
#pragma unroll
                        for (int bj = bk >> 1; bj > 0; bj >>= 1) {
                            const u64 o = __shfl_xor(key, bj);
                            const bool takemin = ((lane & bj) == 0) == ((lane & bk) == 0);
                            key = ((key < o) == takemin) ? key : o;
                        }
                    }
                    lv[cc]  = __int_as_float((int)(unsigned)(key >> 32));
                    li[cc]  = (int)(key & 0xFFFFFFFFu);
                    tau[cc] = __int_as_float(
                        __builtin_amdgcn_readlane(__float_as_int(lv[cc]), NH_ - 1));
                }
            } else {
#pragma unroll
                for (int cc = 0; cc < CPW; ++cc) {
                    const float d2 = rb[lane * LDSP + (w * CPW + cc)];
                    u64 m = __ballot(d2 < tau[cc]);
                    if (m) {
                        while (m) {               // wave-uniform scalar loop, prune-free
                            const int src = __ffsll(m) - 1;  // lowest lane = smallest s
                            m &= m - 1;
                            const float cd = __int_as_float(
                                __builtin_amdgcn_readlane(__float_as_int(d2), src));
                            const int   ci = k * ROWS + src;
                            const unsigned pm = (unsigned)__ballot(lv[cc] <= cd) & 0xFFFFu;
                            const int p2 = __popc(pm);    // p2==16 -> structural no-op
                            const float uv = dpp_shr1_f(lv[cc]);
                            const int   ui = dpp_shr1_i(li[cc]);
                            const bool here  = (lane == p2);
                            const bool shift = (lane > p2) && (lane < NH_);
                            lv[cc] = here ? cd : (shift ? uv : lv[cc]);
                            li[cc] = here ? ci : (shift ? ui : li[cc]);
                        }
                        tau[cc] = __int_as_float(
                            __builtin_amdgcn_readlane(__float_as_int(lv[cc]), NH_ - 1));
                    }
                }
            }
        }
        __syncthreads();                      // phase p+1 staged; phase p buffer free
    }

    // epilogue: write lists + per-wave denom partials
    float dsum = 0.f;
#pragma unroll
    for (int cc = 0; cc < CPW; ++cc) {
        const int t = c0 + w * CPW + cc;
        if (lane < NH_) {
            const float d = sqrtf(lv[cc]) + 1e-15f;
            const float wv = 1.0f / (d * d);
            outW[((size_t)b * T_ + t) * NH_ + lane] = wv;
            outI[((size_t)b * T_ + t) * NH_ + lane] = li[cc];
            dsum += wv;
        }
    }
    if (lane < NH_) red[w * NH_ + lane] = dsum;
    __syncthreads();
    if (tid < NH_) {
        float s = 0.f;
#pragma unroll
        for (int q = 0; q < 16; ++q) s += red[q * NH_ + tid];
        partials[(size_t)bid * NH_ + tid] = s;
    }
}

// ---------------- Kernel B: denom[b][nh] = sum of block partials ----------------
__global__ __launch_bounds__(128) void denom_reduce(
    const float* __restrict__ partials, float* __restrict__ denom)
{
    const int q = blockIdx.x;       // [0,64)
    const int b = q >> 4, j = q & 15;
    const int g = threadIdx.x;      // [0,128) = NCG
    __shared__ float sm[128];
    sm[g] = partials[(size_t)(b * NCG + g) * NH_ + j];
    __syncthreads();
    for (int s = 64; s > 0; s >>= 1) {
        if (g < s) sm[g] += sm[g + s];
        __syncthreads();
    }
    if (g == 0) denom[q] = sm[0];
}

// ---------------- Kernel C: final gather, 16 threads/output ----------------
__global__ __launch_bounds__(256) void out_kernel(
    const float* __restrict__ x,        // [B][S]
    const float* __restrict__ outW,
    const int*   __restrict__ outI,
    const float* __restrict__ denom,    // [B][NH]
    float* __restrict__ out)            // [B][T]
{
    const int gid16 = blockIdx.x * 256 + threadIdx.x;  // [0, 16*B*T)
    const int oid = gid16 >> 4;
    const int q   = gid16 & 15;
    const int i = oid >> 12;
    const int j = oid & 4095;
    const int ih = j >> 8;
    const size_t base = ((size_t)i * T_ + (size_t)(j & 255) * NH_) * NH_ + ih;
    const float w  = outW[base + (size_t)q * NH_];
    const int   id = outI[base + (size_t)q * NH_];
    float v = x[i * S_ + id] * w / denom[(j & 3) * NH_ + q];
    v += __shfl_xor(v, 1);
    v += __shfl_xor(v, 2);
    v += __shfl_xor(v, 4);
    v += __shfl_xor(v, 8);
    if (q == 0) out[oid] = v;
}

extern "C" void kernel_launch(void* const* d_in, const int* in_sizes, int n_in,
                              void* d_out, int out_size, void* d_ws, size_t ws_size,
                              hipStream_t stream) {
    const float* x      = (const float*)d_in[0];
    const float* coords = (const float*)d_in[1];
    float* out = (float*)d_out;

    float* outW     = (float*)d_ws;                                  // 1 MB
    int*   outI     = (int*)(outW + (size_t)B_ * T_ * NH_);          // 1 MB
    float* partials = (float*)(outI + (size_t)B_ * T_ * NH_);        // 32 KB
    float* denom    = partials + (size_t)(B_ * NCG) * NH_;           // 256 B

    topk_scan   <<<B_ * NCG,           1024, 0, stream>>>(coords, outW, outI, partials);
    denom_reduce<<<64,                 128,  0, stream>>>(partials, denom);
    out_kernel  <<<B_ * T_ * 16 / 256, 256,  0, stream>>>(x, outW, outI, denom, out);
}